// Round 1
// baseline (2847.023 us; speedup 1.0000x reference)
//
#include <hip/hip_runtime.h>

// ConvTP: e3nn-style tensor product message passing + segment sum.
// N_NODES=50000, N_EDGES=800000, MUL=32
// inputs: node_features (50000,128) f32, edge_angular (800000,4) f32,
//         edge_index (800000,2) int, tp_weights (800000,160) f32
// output: (50000, 224) f32

#define MUL 32
#define IN_DIM 128
#define W_DIM 160
#define OUT_DIM 224

__device__ __forceinline__ float elem(const float4& v, int i) {
    return ((const float*)&v)[i];
}

__global__ void __launch_bounds__(256) conv_tp_edges(
    const float* __restrict__ nf,
    const float* __restrict__ ang,
    const int*   __restrict__ eidx,
    const float* __restrict__ w,
    float* __restrict__ out,
    int n_edges)
{
    const float INV_SQRT3 = 0.5773502691896258f;
    const float INV_SQRT2 = 0.7071067811865476f;

    int tid = blockIdx.x * blockDim.x + threadIdx.x;
    int e = tid >> 3;        // 8 threads per edge
    int t = tid & 7;         // this thread owns channels [4t, 4t+4)
    if (e >= n_edges) return;

    int src = eidx[2 * e];
    int dst = eidx[2 * e + 1];

    // y0 = y.x ; y1 = (y.y, y.z, y.w). Broadcast load (same 16B per edge-group).
    float4 y = *(const float4*)(ang + 4 * (size_t)e);

    const float* hp = nf + (size_t)src * IN_DIM + 4 * t;
    float4 h0  = *(const float4*)(hp);
    float4 h1a = *(const float4*)(hp + 32);   // h1[m=0]
    float4 h1b = *(const float4*)(hp + 64);   // h1[m=1]
    float4 h1c = *(const float4*)(hp + 96);   // h1[m=2]

    const float* wp = w + (size_t)e * W_DIM + 4 * t;
    float4 w0 = *(const float4*)(wp);
    float4 w1 = *(const float4*)(wp + 32);
    float4 w2 = *(const float4*)(wp + 64);
    float4 w3 = *(const float4*)(wp + 96);
    float4 w4 = *(const float4*)(wp + 128);

    float* op = out + (size_t)dst * OUT_DIM + 4 * t;

    #pragma unroll
    for (int i = 0; i < 4; ++i) {
        float h0c = elem(h0, i);
        float ha  = elem(h1a, i);
        float hb  = elem(h1b, i);
        float hc  = elem(h1c, i);

        float dot = ha * y.y + hb * y.z + hc * y.w;

        // out0e[c] = w0*h0*y0 + w3*(1/sqrt3)*dot
        float o0 = elem(w0, i) * h0c * y.x + elem(w3, i) * (INV_SQRT3 * dot);
        atomicAdd(op + i, o0);

        // out1o[m,c] = w1*h0*y1[m] + w2*h1[m]*y0   (offset 32 + 32*m)
        float w1c = elem(w1, i);
        float w2c = elem(w2, i);
        atomicAdd(op + 32 + i, w1c * h0c * y.y + w2c * ha * y.x);
        atomicAdd(op + 64 + i, w1c * h0c * y.z + w2c * hb * y.x);
        atomicAdd(op + 96 + i, w1c * h0c * y.w + w2c * hc * y.x);

        // cross = h1 x y1 ; out1e[m,c] = w4*(1/sqrt2)*cross[m,c]  (offset 128 + 32*m)
        float w4c = elem(w4, i) * INV_SQRT2;
        atomicAdd(op + 128 + i, w4c * (hb * y.w - hc * y.z));
        atomicAdd(op + 160 + i, w4c * (hc * y.y - ha * y.w));
        atomicAdd(op + 192 + i, w4c * (ha * y.z - hb * y.y));
    }
}

extern "C" void kernel_launch(void* const* d_in, const int* in_sizes, int n_in,
                              void* d_out, int out_size, void* d_ws, size_t ws_size,
                              hipStream_t stream) {
    const float* nf   = (const float*)d_in[0];
    const float* ang  = (const float*)d_in[1];
    const int*   eidx = (const int*)d_in[2];
    const float* w    = (const float*)d_in[3];
    float* out = (float*)d_out;

    int n_edges = in_sizes[2] / 2;   // edge_index has 2 entries per edge

    // Output is accumulated with atomics — must start from zero every call
    // (harness re-poisons d_out to 0xAA before each timed launch).
    hipMemsetAsync(d_out, 0, (size_t)out_size * sizeof(float), stream);

    int threads_total = n_edges * 8;
    int block = 256;
    int grid = (threads_total + block - 1) / block;
    conv_tp_edges<<<grid, block, 0, stream>>>(nf, ang, eidx, w, out, n_edges);
}

// Round 2
// 891.414 us; speedup vs baseline: 3.1938x; 3.1938x over previous
//
#include <hip/hip_runtime.h>

// ConvTP: e3nn-style tensor product message passing + segment sum.
// N_NODES=50000, N_EDGES=800000, MUL=32
// inputs: node_features (50000,128) f32, edge_angular (800000,4) f32,
//         edge_index (800000,2) int32, tp_weights (800000,160) f32
// output: (50000, 224) f32
//
// R1 showed atomic-bound: 179M fp32 atomicAdds -> 2.8GB HBM write traffic,
// 2.32ms with all pipes idle. R2: build CSR-by-dst in d_ws each call, then
// gather per node with register accumulation -> zero output atomics.

#define IN_DIM 128
#define W_DIM 160
#define OUT_DIM 224

__device__ __forceinline__ float elem(const float4& v, int i) {
    return ((const float*)&v)[i];
}

// ---------- Phase 1: histogram of dst ----------
__global__ void __launch_bounds__(256) hist_dst(
    const int* __restrict__ eidx, int* __restrict__ counts, int n_edges)
{
    int e = blockIdx.x * blockDim.x + threadIdx.x;
    if (e >= n_edges) return;
    atomicAdd(counts + eidx[2 * e + 1], 1);
}

// ---------- Phase 2: exclusive scan (single block, 1024 threads) ----------
__global__ void __launch_bounds__(1024) scan_counts(
    int* __restrict__ counts,      // in: counts[n]; out: exclusive offsets[n], counts[n]=total
    int* __restrict__ cursor,      // out: copy of exclusive offsets (mutable for scatter)
    int n)
{
    __shared__ int buf[1024];
    __shared__ int carry_s;
    int tid = threadIdx.x;
    if (tid == 0) carry_s = 0;
    __syncthreads();

    for (int base = 0; base < n; base += 1024) {
        int idx = base + tid;
        int x = (idx < n) ? counts[idx] : 0;
        buf[tid] = x;
        __syncthreads();
        // Hillis-Steele inclusive scan
        #pragma unroll
        for (int off = 1; off < 1024; off <<= 1) {
            int v = (tid >= off) ? buf[tid - off] : 0;
            __syncthreads();
            buf[tid] += v;
            __syncthreads();
        }
        int carry = carry_s;
        int excl = buf[tid] - x + carry;
        if (idx < n) {
            counts[idx] = excl;
            cursor[idx] = excl;
        }
        int chunk_total = buf[1023];
        __syncthreads();
        if (tid == 0) carry_s = carry + chunk_total;
        __syncthreads();
    }
    if (tid == 0) counts[n] = carry_s;   // offsets[n] = total edges
}

// ---------- Phase 3: scatter (edge, src) pairs grouped by dst ----------
__global__ void __launch_bounds__(256) scatter_edges(
    const int* __restrict__ eidx, int* __restrict__ cursor,
    int2* __restrict__ pairs, int n_edges)
{
    int e = blockIdx.x * blockDim.x + threadIdx.x;
    if (e >= n_edges) return;
    int src = eidx[2 * e];
    int dst = eidx[2 * e + 1];
    int pos = atomicAdd(cursor + dst, 1);
    pairs[pos] = make_int2(e, src);
}

// ---------- Phase 4: gather — one wave per node, lane&31 = channel ----------
__global__ void __launch_bounds__(256) gather_nodes(
    const float* __restrict__ nf,
    const float* __restrict__ ang,
    const float* __restrict__ w,
    const int*  __restrict__ offsets,
    const int2* __restrict__ pairs,
    float* __restrict__ out,
    int n_nodes)
{
    const float INV_SQRT3 = 0.5773502691896258f;
    const float INV_SQRT2 = 0.7071067811865476f;

    int gtid = blockIdx.x * blockDim.x + threadIdx.x;
    int node = gtid >> 6;          // one 64-lane wave per node
    if (node >= n_nodes) return;
    int lane = threadIdx.x & 63;
    int c    = lane & 31;          // channel
    int half = lane >> 5;          // two edge streams per wave

    int start = offsets[node];
    int end   = offsets[node + 1];

    float a0 = 0.f, a1 = 0.f, a2 = 0.f, a3 = 0.f, a4 = 0.f, a5 = 0.f, a6 = 0.f;

    for (int i = start + half; i < end; i += 2) {
        int2 p = pairs[i];
        int e = p.x, s = p.y;

        float4 y = *(const float4*)(ang + 4 * (size_t)e);

        const float* hp = nf + (size_t)s * IN_DIM + c;
        float h0 = hp[0];
        float ha = hp[32];
        float hb = hp[64];
        float hc = hp[96];

        const float* wp = w + (size_t)e * W_DIM + c;
        float w0 = wp[0];
        float w1 = wp[32];
        float w2 = wp[64];
        float w3 = wp[96];
        float w4 = wp[128];

        float dot = ha * y.y + hb * y.z + hc * y.w;
        a0 += w0 * h0 * y.x + w3 * (INV_SQRT3 * dot);
        a1 += w1 * h0 * y.y + w2 * ha * y.x;
        a2 += w1 * h0 * y.z + w2 * hb * y.x;
        a3 += w1 * h0 * y.w + w2 * hc * y.x;
        float w4s = w4 * INV_SQRT2;
        a4 += w4s * (hb * y.w - hc * y.z);
        a5 += w4s * (hc * y.y - ha * y.w);
        a6 += w4s * (ha * y.z - hb * y.y);
    }

    // combine the two half-wave edge streams
    a0 += __shfl_xor(a0, 32);
    a1 += __shfl_xor(a1, 32);
    a2 += __shfl_xor(a2, 32);
    a3 += __shfl_xor(a3, 32);
    a4 += __shfl_xor(a4, 32);
    a5 += __shfl_xor(a5, 32);
    a6 += __shfl_xor(a6, 32);

    if (half == 0) {
        float* op = out + (size_t)node * OUT_DIM + c;
        op[0]   = a0;
        op[32]  = a1;
        op[64]  = a2;
        op[96]  = a3;
        op[128] = a4;
        op[160] = a5;
        op[192] = a6;
    }
}

// ---------- Fallback (R1 atomic path) if ws too small ----------
__global__ void __launch_bounds__(256) conv_tp_edges_atomic(
    const float* __restrict__ nf,
    const float* __restrict__ ang,
    const int*   __restrict__ eidx,
    const float* __restrict__ w,
    float* __restrict__ out,
    int n_edges)
{
    const float INV_SQRT3 = 0.5773502691896258f;
    const float INV_SQRT2 = 0.7071067811865476f;

    int tid = blockIdx.x * blockDim.x + threadIdx.x;
    int e = tid >> 3;
    int t = tid & 7;
    if (e >= n_edges) return;

    int src = eidx[2 * e];
    int dst = eidx[2 * e + 1];
    float4 y = *(const float4*)(ang + 4 * (size_t)e);

    const float* hp = nf + (size_t)src * IN_DIM + 4 * t;
    float4 h0  = *(const float4*)(hp);
    float4 h1a = *(const float4*)(hp + 32);
    float4 h1b = *(const float4*)(hp + 64);
    float4 h1c = *(const float4*)(hp + 96);

    const float* wp = w + (size_t)e * W_DIM + 4 * t;
    float4 w0 = *(const float4*)(wp);
    float4 w1 = *(const float4*)(wp + 32);
    float4 w2 = *(const float4*)(wp + 64);
    float4 w3 = *(const float4*)(wp + 96);
    float4 w4 = *(const float4*)(wp + 128);

    float* op = out + (size_t)dst * OUT_DIM + 4 * t;

    #pragma unroll
    for (int i = 0; i < 4; ++i) {
        float h0c = elem(h0, i), ha = elem(h1a, i), hb = elem(h1b, i), hc = elem(h1c, i);
        float dot = ha * y.y + hb * y.z + hc * y.w;
        atomicAdd(op + i, elem(w0, i) * h0c * y.x + elem(w3, i) * (INV_SQRT3 * dot));
        float w1c = elem(w1, i), w2c = elem(w2, i);
        atomicAdd(op + 32 + i, w1c * h0c * y.y + w2c * ha * y.x);
        atomicAdd(op + 64 + i, w1c * h0c * y.z + w2c * hb * y.x);
        atomicAdd(op + 96 + i, w1c * h0c * y.w + w2c * hc * y.x);
        float w4c = elem(w4, i) * INV_SQRT2;
        atomicAdd(op + 128 + i, w4c * (hb * y.w - hc * y.z));
        atomicAdd(op + 160 + i, w4c * (hc * y.y - ha * y.w));
        atomicAdd(op + 192 + i, w4c * (ha * y.z - hb * y.y));
    }
}

extern "C" void kernel_launch(void* const* d_in, const int* in_sizes, int n_in,
                              void* d_out, int out_size, void* d_ws, size_t ws_size,
                              hipStream_t stream) {
    const float* nf   = (const float*)d_in[0];
    const float* ang  = (const float*)d_in[1];
    const int*   eidx = (const int*)d_in[2];
    const float* w    = (const float*)d_in[3];
    float* out = (float*)d_out;

    int n_edges = in_sizes[2] / 2;
    int n_nodes = out_size / OUT_DIM;

    // ws layout (ints): counts/offsets[n_nodes+1] | cursor[n_nodes] | pad | pairs int2[n_edges]
    size_t off_counts = 0;
    size_t off_cursor = off_counts + (size_t)(n_nodes + 1);
    size_t off_pairs  = (off_cursor + (size_t)n_nodes + 1) & ~(size_t)1;  // 8B align
    size_t ints_needed = off_pairs + 2 * (size_t)n_edges;
    size_t bytes_needed = ints_needed * sizeof(int);

    if (ws_size < bytes_needed) {
        // fallback: atomic path (correct, slower)
        hipMemsetAsync(d_out, 0, (size_t)out_size * sizeof(float), stream);
        int threads_total = n_edges * 8;
        int grid = (threads_total + 255) / 256;
        conv_tp_edges_atomic<<<grid, 256, 0, stream>>>(nf, ang, eidx, w, out, n_edges);
        return;
    }

    int* counts  = (int*)d_ws + off_counts;
    int* cursor  = (int*)d_ws + off_cursor;
    int2* pairs  = (int2*)((int*)d_ws + off_pairs);

    hipMemsetAsync(counts, 0, (size_t)(n_nodes + 1) * sizeof(int), stream);

    int grid_e = (n_edges + 255) / 256;
    hist_dst<<<grid_e, 256, 0, stream>>>(eidx, counts, n_edges);
    scan_counts<<<1, 1024, 0, stream>>>(counts, cursor, n_nodes);
    scatter_edges<<<grid_e, 256, 0, stream>>>(eidx, cursor, pairs, n_edges);

    int threads_total = n_nodes * 64;           // one wave per node
    int grid_g = (threads_total + 255) / 256;
    gather_nodes<<<grid_g, 256, 0, stream>>>(nf, ang, w, counts, pairs, out, n_nodes);
}